// Round 4
// baseline (141.799 us; speedup 1.0000x reference)
//
#include <hip/hip_runtime.h>

// Problem: B=8, F=16, N=2048
//   w[b,i,j] = exp(-beta^2 * min(p_i,p_j) * (n_i + n_j - 2*<x_i,x_j>))
//   p_i = exp(2*alpha*log(emb[b,4,i])),  n_i = sum_f emb[b,f,i]^2
// Output 134 MB fp32; fixed harness poison ~104 us; pure-write floor ~20.3 us.
//
// R6: 128x128 tile, conflict-free staging: 142.1 us (kernel ~37). BEST baseline.
// R7: symmetry: neutral -> compute not critical path. REVERTED.
// R8: 32x1024 tile, 4KB store chunks: 148.5 (occupancy crash). REVERTED.
// R9: 2-phase col split: 141.6 -> overlap gain ~= extra As re-read LDS cost.
//     Lesson: phase-split works ONLY if it adds zero LDS re-reads.
// R10 (this): 64x256 tile, wave owns 16 rows x 256 cols. B-frag (4 cols x 16 f
//     = 64 VGPR) cached in registers in phase 0; A-reads are wave-uniform
//     broadcasts (near-free) so 4 row-quad phases re-read A at no cost.
//     Each phase: 4x4 acc -> epilogue -> 1KB-contiguous store per row.
//     Stores post at 4 spread points per block -> drain overlaps compute.
//     nJ/qJ computed in-register during phase 0 (no LDS round-trip).

#define BATCH 8
#define FDIM 16
#define NPT 2048
#define TI 64
#define TJ 256

__global__ __launch_bounds__(256, 4) void qcd_aware_kernel(
    const float* __restrict__ emb,
    const float* __restrict__ alpha_p,
    const float* __restrict__ beta_p,
    float* __restrict__ out)
{
    __shared__ float As[FDIM][TI];   // 4 KB
    __shared__ float Bs[FDIM][TJ];   // 16 KB
    __shared__ float nI[TI], qI[TI]; // 512 B

    const int b  = blockIdx.z;
    const int i0 = blockIdx.y * TI;
    const int j0 = blockIdx.x * TJ;
    const int t    = threadIdx.x;
    const int lane = t & 63;
    const int wv   = t >> 6;         // wave 0..3, owns rows 16*wv..16*wv+15

    const float* base = emb + (size_t)b * FDIM * NPT;

    // ---- stage Bs (16x256) + As (16x64): linear word order, stride-1
    //      ds_write_b128 (conflict-free); global side 1KB contiguous/wave ----
    {
        float* BsF = &Bs[0][0];
        #pragma unroll
        for (int g = 0; g < 4; ++g) {
            const int wd = 4 * t + 1024 * g;   // word in [0, 4096)
            const int f  = wd >> 8;
            const int j  = wd & 255;
            *(float4*)&BsF[wd] = *(const float4*)(base + (size_t)f * NPT + j0 + j);
        }
        {
            const int wd = 4 * t;              // word in [0, 1024)
            const int f  = wd >> 6;
            const int i  = wd & 63;
            *(float4*)(&As[0][0] + wd) = *(const float4*)(base + (size_t)f * NPT + i0 + i);
        }
    }
    __syncthreads();

    const float alpha2 = 2.0f * alpha_p[0];
    const float beta   = beta_p[0];
    // q = -beta^2 * log2(e) * p   (negative scale: min(p_i,p_j) -> max(q_i,q_j))
    const float qscale = -(beta * beta) * 1.4426950408889634f;

    // ---- nI/qI for the 64 i-rows (threads 0..63; column reads are 2-way
    //      bank-aliased = free) ----
    if (t < TI) {
        float s = 0.f;
        #pragma unroll
        for (int f = 0; f < FDIM; ++f) { const float v = As[f][t]; s += v * v; }
        nI[t] = s;
        qI[t] = qscale * __expf(alpha2 * __logf(As[4][t]));
    }
    __syncthreads();

    const int c4    = lane * 4;       // this lane's 4 columns
    const int rbase = wv * 16;        // this wave's row block

    // ---- phase 0: load B-frag into registers (64 VGPR), accumulate nj,
    //      compute rows rbase..rbase+3 ----
    float bc[FDIM][4];
    float nj[4] = {0.f, 0.f, 0.f, 0.f};
    float qj[4];

    float acc0[4][4] = {};
    #pragma unroll
    for (int f = 0; f < FDIM; ++f) {
        const float4 bq = *(const float4*)&Bs[f][c4];
        bc[f][0] = bq.x; bc[f][1] = bq.y; bc[f][2] = bq.z; bc[f][3] = bq.w;
        #pragma unroll
        for (int jj = 0; jj < 4; ++jj) nj[jj] = fmaf(bc[f][jj], bc[f][jj], nj[jj]);
        const float4 a = *(const float4*)&As[f][rbase];   // wave-uniform broadcast
        const float av[4] = {a.x, a.y, a.z, a.w};
        #pragma unroll
        for (int ii = 0; ii < 4; ++ii)
            #pragma unroll
            for (int jj = 0; jj < 4; ++jj)
                acc0[ii][jj] = fmaf(av[ii], bc[f][jj], acc0[ii][jj]);
    }
    #pragma unroll
    for (int jj = 0; jj < 4; ++jj)
        qj[jj] = qscale * __expf(alpha2 * __logf(bc[4][jj]));

    // epilogue + store rows rbase..rbase+3 (1KB contiguous per store instr)
    #pragma unroll
    for (int r = 0; r < 4; ++r) {
        const int row = rbase + r;
        const float ni = nI[row];
        const float qi = qI[row];
        float4 wo; float* wp = (float*)&wo;
        #pragma unroll
        for (int jj = 0; jj < 4; ++jj) {
            const float d = fmaf(-2.0f, acc0[r][jj], ni + nj[jj]);
            wp[jj] = __builtin_amdgcn_exp2f(fmaxf(qi, qj[jj]) * d);
        }
        *(float4*)(out + ((size_t)b * NPT + (size_t)(i0 + row)) * NPT + j0 + c4) = wo;
    }

    // ---- phases 1..3: A re-read via broadcast (near-free), B from registers;
    //      store each row quad as soon as it's done ----
    #pragma unroll
    for (int p = 1; p < 4; ++p) {
        float acc[4][4] = {};
        #pragma unroll
        for (int f = 0; f < FDIM; ++f) {
            const float4 a = *(const float4*)&As[f][rbase + 4 * p];  // broadcast
            const float av[4] = {a.x, a.y, a.z, a.w};
            #pragma unroll
            for (int ii = 0; ii < 4; ++ii)
                #pragma unroll
                for (int jj = 0; jj < 4; ++jj)
                    acc[ii][jj] = fmaf(av[ii], bc[f][jj], acc[ii][jj]);
        }
        #pragma unroll
        for (int r = 0; r < 4; ++r) {
            const int row = rbase + 4 * p + r;
            const float ni = nI[row];
            const float qi = qI[row];
            float4 wo; float* wp = (float*)&wo;
            #pragma unroll
            for (int jj = 0; jj < 4; ++jj) {
                const float d = fmaf(-2.0f, acc[r][jj], ni + nj[jj]);
                wp[jj] = __builtin_amdgcn_exp2f(fmaxf(qi, qj[jj]) * d);
            }
            *(float4*)(out + ((size_t)b * NPT + (size_t)(i0 + row)) * NPT + j0 + c4) = wo;
        }
    }
}

extern "C" void kernel_launch(void* const* d_in, const int* in_sizes, int n_in,
                              void* d_out, int out_size, void* d_ws, size_t ws_size,
                              hipStream_t stream) {
    const float* emb     = (const float*)d_in[0];
    const float* alpha_p = (const float*)d_in[1];
    const float* beta_p  = (const float*)d_in[2];
    float* out = (float*)d_out;

    dim3 grid(NPT / TJ, NPT / TI, BATCH);   // 8 x 32 x 8 = 2048 blocks
    dim3 block(256);
    qcd_aware_kernel<<<grid, block, 0, stream>>>(emb, alpha_p, beta_p, out);
}